// Round 5
// baseline (71.875 us; speedup 1.0000x reference)
//
#include <hip/hip_runtime.h>

#define CHUNK 512   // points per block (staged in LDS), 2 KB
#define GRP   32    // group-tracking granularity
#define Q     2     // queries per thread (register blocking)
#define QB    4     // fallback: queries per block

// ---------------------------------------------------------------------------
// init: best[q] = ~0 (workspace is poisoned 0xAA by the harness every call)
// ---------------------------------------------------------------------------
__global__ __launch_bounds__(256, 8)
void nn_init_kernel(unsigned long long* __restrict__ best, int B) {
    int i = blockIdx.x * 256 + threadIdx.x;
    if (i < B) best[i] = ~0ULL;
}

// ---------------------------------------------------------------------------
// main: Q=2 queries per THREAD (q0 = qg*512 + tid, q1 = q0 + 256); block
// stages a 512-pt chunk in LDS; broadcast ds_read_b128 delivers 4 points to
// all lanes, feeding 12 VALU ops (2 queries x (4 sub + 2 min3-with-|abs|)).
// Register blocking halves LDS-pipe issue demand vs 1 query/lane -> VALU-bound.
//
// Distance-only min, NO per-point index tracking. grp = last group that
// strictly lowered the running min == FIRST group containing the final min
// (min only strictly decreases; ties never update). Epilogue rescans the
// winning 32 points descending, keeping the smallest index whose recomputed
// distance is bit-identical (identical v_sub+|abs| sequence -> identical bits).
// Cross-chunk merge: atomicMin on u64 (dist_bits<<32 | global_idx) —
// associative -> deterministic; preserves numpy first-index tie-break
// (dist >= 0 so f32 bits are monotone; idx ascending).
// ---------------------------------------------------------------------------
__global__ __launch_bounds__(256, 8)
void nn_main_kernel(const float* __restrict__ x,
                    const float* __restrict__ pts,
                    unsigned long long* __restrict__ best,
                    int qg_shift)    // nqg = B/(256*Q), pow2
{
    __shared__ float lds[CHUNK];
    const int tid = threadIdx.x;
    const int qg = blockIdx.x & ((1 << qg_shift) - 1);  // query-group (512 q)
    const int ck = blockIdx.x >> qg_shift;              // chunk index

    // stage chunk: 256 threads x float2 = 512 floats, coalesced
    reinterpret_cast<float2*>(lds)[tid] =
        reinterpret_cast<const float2*>(pts)[ck * (CHUNK / 2) + tid];

    const int q0 = (qg << 9) + tid;     // and q1 = q0 + 256
    const float xq0 = x[q0];
    const float xq1 = x[q0 + 256];

    __syncthreads();

    const float inf = __builtin_inff();
    float bdA0 = inf, bdB0 = inf, prev0 = inf;
    float bdA1 = inf, bdB1 = inf, prev1 = inf;
    int grp0 = 0, grp1 = 0;

    const float4* __restrict__ l4 = reinterpret_cast<const float4*>(lds);

    #pragma unroll 2
    for (int g = 0; g < CHUNK / GRP; ++g) {
        #pragma unroll
        for (int t = 0; t < GRP / 4; ++t) {
            float4 v = l4[g * (GRP / 4) + t];    // uniform addr -> broadcast
            bdA0 = fminf(fminf(fabsf(v.x - xq0), fabsf(v.y - xq0)), bdA0);
            bdB0 = fminf(fminf(fabsf(v.z - xq0), fabsf(v.w - xq0)), bdB0);
            bdA1 = fminf(fminf(fabsf(v.x - xq1), fabsf(v.y - xq1)), bdA1);
            bdB1 = fminf(fminf(fabsf(v.z - xq1), fabsf(v.w - xq1)), bdB1);
        }
        float cur0 = fminf(bdA0, bdB0);
        float cur1 = fminf(bdA1, bdB1);
        grp0 = (cur0 < prev0) ? g : grp0;  prev0 = cur0;
        grp1 = (cur1 < prev1) ? g : grp1;  prev1 = cur1;
    }

    // Epilogue: first index in winning group with dist bit-equal to the min.
    // Per-lane LDS gather (grp differs per lane) — once per chunk, cheap.
    int bi0 = 0, bi1 = 0;
    const float4* __restrict__ pg0 = l4 + grp0 * (GRP / 4);
    const float4* __restrict__ pg1 = l4 + grp1 * (GRP / 4);
    #pragma unroll
    for (int t = GRP / 4 - 1; t >= 0; --t) {     // descending -> first wins
        float4 v = pg0[t];
        bi0 = (fabsf(v.w - xq0) == prev0) ? 4 * t + 3 : bi0;
        bi0 = (fabsf(v.z - xq0) == prev0) ? 4 * t + 2 : bi0;
        bi0 = (fabsf(v.y - xq0) == prev0) ? 4 * t + 1 : bi0;
        bi0 = (fabsf(v.x - xq0) == prev0) ? 4 * t + 0 : bi0;
    }
    #pragma unroll
    for (int t = GRP / 4 - 1; t >= 0; --t) {
        float4 v = pg1[t];
        bi1 = (fabsf(v.w - xq1) == prev1) ? 4 * t + 3 : bi1;
        bi1 = (fabsf(v.z - xq1) == prev1) ? 4 * t + 2 : bi1;
        bi1 = (fabsf(v.y - xq1) == prev1) ? 4 * t + 1 : bi1;
        bi1 = (fabsf(v.x - xq1) == prev1) ? 4 * t + 0 : bi1;
    }

    const unsigned base = (unsigned)(ck * CHUNK);
    const unsigned long long key0 =
        ((unsigned long long)__float_as_uint(prev0) << 32) |
        (base + (unsigned)(grp0 * GRP + bi0));
    const unsigned long long key1 =
        ((unsigned long long)__float_as_uint(prev1) << 32) |
        (base + (unsigned)(grp1 * GRP + bi1));
    atomicMin(&best[q0], key0);          // coalesced within wave
    atomicMin(&best[q0 + 256], key1);
}

// ---------------------------------------------------------------------------
// gather: out[q] = acc[idx(best[q])]
// ---------------------------------------------------------------------------
__global__ __launch_bounds__(256, 8)
void nn_gather_kernel(const unsigned long long* __restrict__ best,
                      const float* __restrict__ acc,
                      float* __restrict__ out, int B) {
    int i = blockIdx.x * 256 + threadIdx.x;
    if (i < B) out[i] = acc[(unsigned)(best[i] & 0xffffffffULL)];
}

// ---------------------------------------------------------------------------
// Fallback (round-1 kernel): one query per wave, vector loads. Generic.
// ---------------------------------------------------------------------------
__global__ __launch_bounds__(256, 4)
void nn_kernel(const float* __restrict__ x,
               const float* __restrict__ pts,
               const float* __restrict__ acc,
               float* __restrict__ out,
               int B, int N) {
    const int lane = threadIdx.x & 63;
    const int wave = threadIdx.x >> 6;
    const int q    = blockIdx.x * QB + wave;
    if (q >= B) return;

    const float xq = x[q];
    const int G = N >> 2;
    const int J = G >> 6;

    float bd0 = __builtin_inff(), bd1 = __builtin_inff(),
          bd2 = __builtin_inff(), bd3 = __builtin_inff();
    int   bj0 = 0, bj1 = 0, bj2 = 0, bj3 = 0;

    const float4* __restrict__ p4 = reinterpret_cast<const float4*>(pts);

    #pragma unroll 4
    for (int j = 0; j < J; ++j) {
        float4 v = p4[lane + 64 * j];
        float d0 = fabsf(v.x - xq);
        float d1 = fabsf(v.y - xq);
        float d2 = fabsf(v.z - xq);
        float d3 = fabsf(v.w - xq);
        if (d0 < bd0) { bd0 = d0; bj0 = j; }
        if (d1 < bd1) { bd1 = d1; bj1 = j; }
        if (d2 < bd2) { bd2 = d2; bj2 = j; }
        if (d3 < bd3) { bd3 = d3; bj3 = j; }
    }

    unsigned long long key;
    {
        unsigned i0 = (unsigned)(4 * (lane + 64 * bj0) + 0);
        unsigned i1 = (unsigned)(4 * (lane + 64 * bj1) + 1);
        unsigned i2 = (unsigned)(4 * (lane + 64 * bj2) + 2);
        unsigned i3 = (unsigned)(4 * (lane + 64 * bj3) + 3);
        unsigned long long k0 = ((unsigned long long)__float_as_uint(bd0) << 32) | i0;
        unsigned long long k1 = ((unsigned long long)__float_as_uint(bd1) << 32) | i1;
        unsigned long long k2 = ((unsigned long long)__float_as_uint(bd2) << 32) | i2;
        unsigned long long k3 = ((unsigned long long)__float_as_uint(bd3) << 32) | i3;
        key = k0 < k1 ? k0 : k1;
        unsigned long long k23 = k2 < k3 ? k2 : k3;
        key = key < k23 ? key : k23;
    }

    for (int i = J * 256 + lane; i < N; i += 64) {
        float d = fabsf(pts[i] - xq);
        unsigned long long k = ((unsigned long long)__float_as_uint(d) << 32) | (unsigned)i;
        key = key < k ? key : k;
    }

    #pragma unroll
    for (int off = 1; off < 64; off <<= 1) {
        unsigned long long o = __shfl_xor(key, off, 64);
        key = key < o ? key : o;
    }

    if (lane == 0) {
        out[q] = acc[(unsigned)(key & 0xffffffffULL)];
    }
}

extern "C" void kernel_launch(void* const* d_in, const int* in_sizes, int n_in,
                              void* d_out, int out_size, void* d_ws, size_t ws_size,
                              hipStream_t stream) {
    const float* x   = (const float*)d_in[0];
    const float* pts = (const float*)d_in[1];
    const float* acc = (const float*)d_in[2];
    float* out = (float*)d_out;
    const int B = in_sizes[0];
    const int N = in_sizes[1];

    const int nqg = B >> 9;                      // query groups of 512 (Q=2)
    const bool pow2 = (nqg > 0) && ((nqg & (nqg - 1)) == 0);
    const bool fast = pow2 && (B % 512 == 0) && (N % CHUNK == 0) &&
                      d_ws != nullptr && ws_size >= (size_t)B * 8;

    if (fast) {
        int qg_shift = 0;
        while ((1 << qg_shift) < nqg) ++qg_shift;
        const int nchunk = N / CHUNK;
        unsigned long long* best = (unsigned long long*)d_ws;

        hipLaunchKernelGGL(nn_init_kernel, dim3((B + 255) / 256), dim3(256), 0,
                           stream, best, B);
        hipLaunchKernelGGL(nn_main_kernel, dim3(nchunk * nqg), dim3(256), 0,
                           stream, x, pts, best, qg_shift);
        hipLaunchKernelGGL(nn_gather_kernel, dim3((B + 255) / 256), dim3(256),
                           0, stream, best, acc, out, B);
    } else {
        const int blocks = (B + QB - 1) / QB;
        hipLaunchKernelGGL(nn_kernel, dim3(blocks), dim3(256), 0, stream,
                           x, pts, acc, out, B, N);
    }
}